// Round 4
// baseline (11004.331 us; speedup 1.0000x reference)
//
#include <hip/hip_runtime.h>
#include <hip/hip_cooperative_groups.h>
#include <cstdint>
#include <cstddef>

// Sinkhorn: B=64, P=1024, T=1024, 50 iterations.
// R6: persistent cooperative kernel = R4 skeleton (grid.sync: proven to
// execute under this harness/capture) + R5 coherence fixes (the R4 bug):
//   - accumulator zeroing via agent-scope atomic stores (write-through;
//     no dirty per-XCD L2 lines to later clobber atomics),
//   - accumulator reads via agent-scope atomic loads (bypass stale L2),
//   - accumulation via device-scope unsafeAtomicAdd (proven in R3).
// All other data (K8 rows, pred, C, out) is block-private: plain ops.
// No custom spin barriers, no hipMemsetAsync. Coop-launch failure falls
// back to the proven R3 multi-launch fp8 path (passed, 1367us).

namespace cg = cooperative_groups;

#define DEVI static __device__ __forceinline__

// fp8 e4m3 encode (sign=0). Input pre-scaled by 256: f in (0, 256].
DEVI unsigned char f2fp8(float f) {
    if (f >= 0.015625f) {                      // normal fp8
        unsigned u = __float_as_uint(f);
        u += 0x7FFFFu + ((u >> 20) & 1u);      // RNE into 3-bit mantissa
        int e = (int)(u >> 23) - 127;
        return (unsigned char)(((e + 7) << 3) | ((u >> 20) & 7u));
    } else {                                   // subnormal: round(f*512)
        int n = (int)(f * 512.0f + 0.5f);      // n==8 aliases to e=1,m=0: correct
        return (unsigned char)n;
    }
}
// raw decode: returns K * 2^-112 (sums multiplied by 2^112 once)
DEVI float fp8raw(unsigned b) { return __uint_as_float((b & 0x7Fu) << 20); }
#define FP8_SCALE 0x1.0p112f

DEVI void atomicAddF(float* p, float v) {
#ifdef __HIP_PLATFORM_AMD__
    unsafeAtomicAdd(p, v);   // native global_atomic_add_f32, device-coherent
#else
    atomicAdd(p, v);
#endif
}
DEVI float cohLoad(const float* p) {
    return __hip_atomic_load(p, __ATOMIC_RELAXED, __HIP_MEMORY_SCOPE_AGENT);
}
DEVI void cohStore(float* p, float v) {
    __hip_atomic_store(p, v, __ATOMIC_RELAXED, __HIP_MEMORY_SCOPE_AGENT);
}

// Persistent fused Sinkhorn. grid MUST be 1024 x 256 (4 blocks/CU
// co-resident: __launch_bounds__(256,4) -> VGPR<=128; LDS ~22KB*4 < 160KB).
// Block bx: batch b = bx>>4, row-group rb = bx&15 -> rows rb*64..rb*64+63.
// Cross-block traffic is ONLY the per-batch 4KB accumulators (coherent ops).
__global__ __launch_bounds__(256, 4) void k_sink(const float4* __restrict__ C4,
        const float* __restrict__ regp, unsigned* __restrict__ K8u,
        float* __restrict__ accs, const float* __restrict__ tgt,
        const float* __restrict__ pred, float4* __restrict__ out4) {
    cg::grid_group grid = cg::this_grid();
    __shared__ float sv[1024];
    __shared__ float red[4 * 1088];   // per-wave partials, stride 17: 2-way banks
    __shared__ float su64[64];        // final u for this block's rows
    __shared__ float spred[64];       // pred for this block's rows
    const int tid = threadIdx.x;
    const int bx = blockIdx.x;
    const int b = bx >> 4;
    const int rb = bx & 15;
    const float negi = -1.0f / regp[0];
    const unsigned char* K8 = (const unsigned char*)K8u;
    const float* tg = tgt + (b << 10);

    // ---- phase A: zero this batch's slices of all 3 accumulators ----
    // (coherent stores: write-through, no dirty lines vs later atomics)
    if (tid < 192) {
        const int buf = tid >> 6, j = tid & 63;
        cohStore(accs + (size_t)buf * 65536 + (b << 10) + (rb << 6) + j, 0.f);
    }
    if (tid < 64) spred[tid] = pred[(b << 10) + (rb << 6) + tid];
    grid.sync();

    // ---- phase B: encode this block's 64 rows; fold acc0 = K^T 1 ----
    {
        float a0 = 0.f, a1 = 0.f, a2 = 0.f, a3 = 0.f;
        const size_t rowbase = (((size_t)b) << 18) + ((size_t)rb << 14);  // float4 units
        #pragma unroll 4
        for (int r = 0; r < 64; ++r) {
            const size_t idx = rowbase + ((size_t)r << 8) + tid;
            float4 c = C4[idx];
            unsigned p = (unsigned)f2fp8(__expf(c.x * negi) * 256.f)
                       | ((unsigned)f2fp8(__expf(c.y * negi) * 256.f) << 8)
                       | ((unsigned)f2fp8(__expf(c.z * negi) * 256.f) << 16)
                       | ((unsigned)f2fp8(__expf(c.w * negi) * 256.f) << 24);
            K8u[idx] = p;            // block-private rows: plain store OK
            a0 += fp8raw(p);       a1 += fp8raw(p >> 8);
            a2 += fp8raw(p >> 16); a3 += fp8raw(p >> 24);
        }
        float* a = accs + (b << 10) + (tid << 2);
        atomicAddF(a + 0, a0); atomicAddF(a + 1, a1);
        atomicAddF(a + 2, a2); atomicAddF(a + 3, a3);
    }
    __threadfence();
    grid.sync();

    // ---- phase C: 50 fused Sinkhorn iterations ----
    const int w = tid >> 6, l = tid & 63;
    const int row0 = (b << 10) + (rb << 6) + (w << 4);
    for (int it = 0; it < 50; ++it) {
        const float* ain = accs + (size_t)(it % 3) * 65536 + (b << 10);
        float* aout = accs + (size_t)((it + 1) % 3) * 65536 + (b << 10);
        float* az = accs + (size_t)((it + 2) % 3) * 65536 + (b << 10) + (rb << 6);
        // v[t] = tgt/(acc_in*SCALE); coherent loads (atomics wrote these)
        #pragma unroll
        for (int q = 0; q < 4; ++q) {
            const int t = tid + (q << 8);
            sv[t] = tg[t] / (cohLoad(ain + t) * FP8_SCALE);
        }
        // zero iteration-(i+1)'s accumulate target (this block's 64-slice;
        // safe: buffer was last READ at it-1, all readers passed last sync)
        if (tid < 64) cohStore(az + tid, 0.f);
        __syncthreads();

        const float4 v0 = *(const float4*)(sv + (l << 4));
        const float4 v1 = *(const float4*)(sv + (l << 4) + 4);
        const float4 v2 = *(const float4*)(sv + (l << 4) + 8);
        const float4 v3 = *(const float4*)(sv + (l << 4) + 12);
        float r00=0,r01=0,r02=0,r03=0,r04=0,r05=0,r06=0,r07=0;
        float r08=0,r09=0,r10=0,r11=0,r12=0,r13=0,r14=0,r15=0;
        #pragma unroll 2
        for (int r = 0; r < 16; ++r) {
            const size_t row = (size_t)row0 + r;
            const uint4 k = ((const uint4*)(K8 + (row << 10)))[l];
            const float f0 = fp8raw(k.x),       f1 = fp8raw(k.x >> 8);
            const float f2 = fp8raw(k.x >> 16), f3 = fp8raw(k.x >> 24);
            const float f4 = fp8raw(k.y),       f5 = fp8raw(k.y >> 8);
            const float f6 = fp8raw(k.y >> 16), f7 = fp8raw(k.y >> 24);
            const float f8 = fp8raw(k.z),       f9 = fp8raw(k.z >> 8);
            const float fa = fp8raw(k.z >> 16), fb = fp8raw(k.z >> 24);
            const float fc = fp8raw(k.w),       fd = fp8raw(k.w >> 8);
            const float fe = fp8raw(k.w >> 16), ff = fp8raw(k.w >> 24);
            // 4 independent FMA chains for ILP, then 2-level combine
            float sA = f0 * v0.x, sB = f1 * v0.y, sC = f2 * v0.z, sD = f3 * v0.w;
            sA += f4 * v1.x; sB += f5 * v1.y; sC += f6 * v1.z; sD += f7 * v1.w;
            sA += f8 * v2.x; sB += f9 * v2.y; sC += fa * v2.z; sD += fb * v2.w;
            sA += fc * v3.x; sB += fd * v3.y; sC += fe * v3.z; sD += ff * v3.w;
            float s = (sA + sB) + (sC + sD);
            #pragma unroll
            for (int m = 32; m >= 1; m >>= 1) s += __shfl_xor(s, m, 64);
            const float un = spred[(rb ? 0 : 0) + (w << 4) + r] / (s * FP8_SCALE);
            if (it == 49 && l == 0) su64[(w << 4) + r] = un;
            r00 += f0*un; r01 += f1*un; r02 += f2*un; r03 += f3*un;
            r04 += f4*un; r05 += f5*un; r06 += f6*un; r07 += f7*un;
            r08 += f8*un; r09 += f9*un; r10 += fa*un; r11 += fb*un;
            r12 += fc*un; r13 += fd*un; r14 += fe*un; r15 += ff*un;
        }
        {   // lane l owns t = 16l+j; stride-17: bank = (17l+j)%32, 2-way only
            const int base = w * 1088 + l * 17;
            red[base + 0] = r00;  red[base + 1] = r01;  red[base + 2] = r02;  red[base + 3] = r03;
            red[base + 4] = r04;  red[base + 5] = r05;  red[base + 6] = r06;  red[base + 7] = r07;
            red[base + 8] = r08;  red[base + 9] = r09;  red[base + 10] = r10; red[base + 11] = r11;
            red[base + 12] = r12; red[base + 13] = r13; red[base + 14] = r14; red[base + 15] = r15;
        }
        __syncthreads();
        #pragma unroll
        for (int q = 0; q < 4; ++q) {
            const int t = tid + (q << 8);
            const int idx = (t >> 4) * 17 + (t & 15);
            float s2 = red[idx] + red[idx + 1088] + red[idx + 2176] + red[idx + 3264];
            atomicAddF(aout + t, s2);   // 16 adds per address total
        }
        __threadfence();
        grid.sync();
    }

    // ---- phase D: final v from acc[50%3] = acc[2]; P = u*exp(-C/reg)*v ----
    {
        const float* afin = accs + (size_t)2 * 65536 + (b << 10);
        #pragma unroll
        for (int q = 0; q < 4; ++q) {
            const int t = tid + (q << 8);
            sv[t] = tg[t] / (cohLoad(afin + t) * FP8_SCALE);
        }
        __syncthreads();
        const float4 vv = ((const float4*)sv)[tid];
        const size_t rowbase = (((size_t)b) << 18) + ((size_t)rb << 14);
        #pragma unroll 2
        for (int r = 0; r < 64; ++r) {
            const float up = su64[r];
            const size_t idx = rowbase + ((size_t)r << 8) + tid;
            float4 c = C4[idx];
            out4[idx] = make_float4(up * __expf(c.x * negi) * vv.x,
                                    up * __expf(c.y * negi) * vv.y,
                                    up * __expf(c.z * negi) * vv.z,
                                    up * __expf(c.w * negi) * vv.w);
        }
    }
}

// ======== fallback 1: proven R3 multi-launch fp8 path (1367us) ========
__global__ __launch_bounds__(256) void k_zero(float* __restrict__ p, int n) {
    int i = blockIdx.x * 256 + threadIdx.x;
    if (i < n) p[i] = 0.0f;
}
__global__ __launch_bounds__(256) void k_ones(float* __restrict__ p, int n) {
    int i = blockIdx.x * 256 + threadIdx.x;
    if (i < n) p[i] = 1.0f;
}

__global__ __launch_bounds__(256) void k_exp8c(const float4* __restrict__ C4,
        const float* __restrict__ regp, unsigned* __restrict__ K8,
        float* __restrict__ acc0) {
    const float negi = -1.0f / regp[0];
    const int tid = threadIdx.x;
    const int b = blockIdx.x >> 4;
    const int r0 = blockIdx.x & 15;
    float a0 = 0.f, a1 = 0.f, a2 = 0.f, a3 = 0.f;
    const size_t bbase = (((size_t)b) << 18) + tid;   // float4 units
    #pragma unroll 4
    for (int k = 0; k < 64; ++k) {
        const size_t idx = bbase + ((size_t)((k << 4) + r0) << 8);
        float4 c = C4[idx];
        unsigned p = (unsigned)f2fp8(__expf(c.x * negi) * 256.f)
                   | ((unsigned)f2fp8(__expf(c.y * negi) * 256.f) << 8)
                   | ((unsigned)f2fp8(__expf(c.z * negi) * 256.f) << 16)
                   | ((unsigned)f2fp8(__expf(c.w * negi) * 256.f) << 24);
        K8[idx] = p;
        a0 += fp8raw(p);       a1 += fp8raw(p >> 8);
        a2 += fp8raw(p >> 16); a3 += fp8raw(p >> 24);
    }
    float* a = acc0 + (b << 10) + (tid << 2);
    atomicAddF(a + 0, a0); atomicAddF(a + 1, a1);
    atomicAddF(a + 2, a2); atomicAddF(a + 3, a3);
}

__global__ __launch_bounds__(256) void k_fused(const unsigned char* __restrict__ K8,
        const float* __restrict__ acc_in, float* __restrict__ acc_out,
        float* __restrict__ acc_z,
        const float* __restrict__ tgt, const float* __restrict__ pred,
        float* __restrict__ u) {
    __shared__ float sv[1024];
    __shared__ float red[4 * 1088];
    const int tid = threadIdx.x;
    const int b = blockIdx.x >> 4;
    const int rb = blockIdx.x & 15;
    {
        const float* ai = acc_in + (b << 10);
        const float* tg = tgt + (b << 10);
        #pragma unroll
        for (int q = 0; q < 4; ++q) {
            const int t = tid + (q << 8);
            sv[t] = tg[t] / (ai[t] * FP8_SCALE);
        }
        if (tid < 64) acc_z[(blockIdx.x << 6) + tid] = 0.f;
    }
    __syncthreads();
    const int w = tid >> 6, l = tid & 63;
    const int row0 = (b << 10) + (rb << 6) + (w << 4);
    const float4 v0 = *(const float4*)(sv + (l << 4));
    const float4 v1 = *(const float4*)(sv + (l << 4) + 4);
    const float4 v2 = *(const float4*)(sv + (l << 4) + 8);
    const float4 v3 = *(const float4*)(sv + (l << 4) + 12);
    float r00=0,r01=0,r02=0,r03=0,r04=0,r05=0,r06=0,r07=0;
    float r08=0,r09=0,r10=0,r11=0,r12=0,r13=0,r14=0,r15=0;
    #pragma unroll 2
    for (int r = 0; r < 16; ++r) {
        const size_t row = (size_t)row0 + r;
        const uint4 k = ((const uint4*)(K8 + (row << 10)))[l];
        const float f0 = fp8raw(k.x),       f1 = fp8raw(k.x >> 8);
        const float f2 = fp8raw(k.x >> 16), f3 = fp8raw(k.x >> 24);
        const float f4 = fp8raw(k.y),       f5 = fp8raw(k.y >> 8);
        const float f6 = fp8raw(k.y >> 16), f7 = fp8raw(k.y >> 24);
        const float f8 = fp8raw(k.z),       f9 = fp8raw(k.z >> 8);
        const float fa = fp8raw(k.z >> 16), fb = fp8raw(k.z >> 24);
        const float fc = fp8raw(k.w),       fd = fp8raw(k.w >> 8);
        const float fe = fp8raw(k.w >> 16), ff = fp8raw(k.w >> 24);
        float s = f0*v0.x + f1*v0.y + f2*v0.z + f3*v0.w
                + f4*v1.x + f5*v1.y + f6*v1.z + f7*v1.w
                + f8*v2.x + f9*v2.y + fa*v2.z + fb*v2.w
                + fc*v3.x + fd*v3.y + fe*v3.z + ff*v3.w;
        #pragma unroll
        for (int m = 32; m >= 1; m >>= 1) s += __shfl_xor(s, m, 64);
        const float un = pred[row] / (s * FP8_SCALE);
        if (l == 0) u[row] = un;
        r00 += f0*un; r01 += f1*un; r02 += f2*un; r03 += f3*un;
        r04 += f4*un; r05 += f5*un; r06 += f6*un; r07 += f7*un;
        r08 += f8*un; r09 += f9*un; r10 += fa*un; r11 += fb*un;
        r12 += fc*un; r13 += fd*un; r14 += fe*un; r15 += ff*un;
    }
    {
        const int base = w * 1088 + l * 17;
        red[base + 0] = r00;  red[base + 1] = r01;  red[base + 2] = r02;  red[base + 3] = r03;
        red[base + 4] = r04;  red[base + 5] = r05;  red[base + 6] = r06;  red[base + 7] = r07;
        red[base + 8] = r08;  red[base + 9] = r09;  red[base + 10] = r10; red[base + 11] = r11;
        red[base + 12] = r12; red[base + 13] = r13; red[base + 14] = r14; red[base + 15] = r15;
    }
    __syncthreads();
    float* ao = acc_out + (b << 10);
    #pragma unroll
    for (int q = 0; q < 4; ++q) {
        const int t = tid + (q << 8);
        const int idx = (t >> 4) * 17 + (t & 15);
        float s2 = red[idx] + red[idx + 1088] + red[idx + 2176] + red[idx + 3264];
        atomicAddF(ao + t, s2);
    }
}

__global__ __launch_bounds__(256) void k_vfin(const float* __restrict__ acc,
        const float* __restrict__ tgt, float* __restrict__ v, int n) {
    int i = blockIdx.x * 256 + threadIdx.x;
    if (i < n) v[i] = tgt[i] / (acc[i] * FP8_SCALE);
}

__global__ __launch_bounds__(256) void k_poutUC(const float* __restrict__ C,
        const float* __restrict__ regp, const float* __restrict__ u,
        const float* __restrict__ v, float* __restrict__ out) {
    const size_t row = blockIdx.x;
    const int b = (int)(row >> 10);
    const int t = threadIdx.x << 2;
    const float up = u[row];
    const float negi = -1.0f / regp[0];
    const float4 vv = *(const float4*)(v + (b << 10) + t);
    const float4 c4 = *(const float4*)(C + (row << 10) + t);
    float4 o = make_float4(up * __expf(c4.x * negi) * vv.x,
                           up * __expf(c4.y * negi) * vv.y,
                           up * __expf(c4.z * negi) * vv.z,
                           up * __expf(c4.w * negi) * vv.w);
    *(float4*)(out + (row << 10) + t) = o;
}

// ======== fallback 2: tiny workspace, recompute exp from C each pass ========
__global__ __launch_bounds__(256) void k_ktuC(const float* __restrict__ C,
        const float* __restrict__ regp, const float* __restrict__ u,
        const float* __restrict__ tgt, float* __restrict__ v) {
    __shared__ float su[1024];
    __shared__ float4 red[256];
    const int b = blockIdx.y;
    const int t0 = blockIdx.x * 128;
    const int tid = threadIdx.x;
    ((float4*)su)[tid] = ((const float4*)(u + (b << 10)))[tid];
    __syncthreads();
    const int tt = tid & 31;
    const int pg = tid >> 5;
    const int t = t0 + tt * 4;
    float4 acc = make_float4(0.f, 0.f, 0.f, 0.f);
    const float negi = -1.0f / regp[0];
    const float* Cp = C + (((size_t)b) << 20) + ((size_t)pg << 10) + t;
    #pragma unroll 4
    for (int p = pg; p < 1024; p += 8) {
        float4 c4 = *(const float4*)Cp;
        float up = su[p];
        acc.x += __expf(c4.x * negi) * up;
        acc.y += __expf(c4.y * negi) * up;
        acc.z += __expf(c4.z * negi) * up;
        acc.w += __expf(c4.w * negi) * up;
        Cp += (size_t)8 << 10;
    }
    red[tid] = acc;
    __syncthreads();
    if (tid < 32) {
        float4 s = red[tid];
        #pragma unroll
        for (int g = 1; g < 8; ++g) {
            float4 r = red[tid + (g << 5)];
            s.x += r.x; s.y += r.y; s.z += r.z; s.w += r.w;
        }
        const int tw = t0 + tid * 4;
        const float4 tg = *(const float4*)(tgt + (b << 10) + tw);
        *(float4*)(v + (b << 10) + tw) =
            make_float4(tg.x / s.x, tg.y / s.y, tg.z / s.z, tg.w / s.w);
    }
}

__global__ __launch_bounds__(256) void k_kvC(const float* __restrict__ C,
        const float* __restrict__ regp, const float* __restrict__ v,
        const float* __restrict__ pred, float* __restrict__ u) {
    __shared__ float sv[1024];
    const int tid = threadIdx.x;
    const int row0 = blockIdx.x << 2;
    const int b = row0 >> 10;
    ((float4*)sv)[tid] = ((const float4*)(v + (b << 10)))[tid];
    __syncthreads();
    const int w = tid >> 6, l = tid & 63;
    const size_t row = (size_t)row0 + w;
    float s = 0.f;
    const float negi = -1.0f / regp[0];
    const float* Cr = C + (row << 10);
    #pragma unroll
    for (int i = 0; i < 4; ++i) {
        const int t = (i << 8) + (l << 2);
        float4 c4 = *(const float4*)(Cr + t);
        float4 vv = *(const float4*)(sv + t);
        s += __expf(c4.x * negi) * vv.x + __expf(c4.y * negi) * vv.y
           + __expf(c4.z * negi) * vv.z + __expf(c4.w * negi) * vv.w;
    }
    #pragma unroll
    for (int m = 32; m >= 1; m >>= 1) s += __shfl_xor(s, m, 64);
    if (l == 0) u[row] = pred[row] / s;
}

extern "C" void kernel_launch(void* const* d_in, const int* in_sizes, int n_in,
                              void* d_out, int out_size, void* d_ws, size_t ws_size,
                              hipStream_t stream) {
    const float* pred = (const float*)d_in[0];
    const float* tgt  = (const float*)d_in[1];
    const float* C    = (const float*)d_in[2];
    const float* regp = (const float*)d_in[3];
    float* out = (float*)d_out;

    const size_t k8b  = (size_t)64 * 1024 * 1024;         // 64 MB fp8 K
    const size_t accb = (size_t)3 * 65536 * 4;            // 768 KB acc[3]
    char* ws = (char*)d_ws;
    const dim3 blk(256);

    if (ws_size >= k8b + accb + (size_t)2 * 65536 * 4) {
        unsigned* K8u = (unsigned*)ws;
        float* accs = (float*)(ws + k8b);
        const float4* C4 = (const float4*)C;
        float4* out4 = (float4*)out;

        void* args[] = { (void*)&C4, (void*)&regp, (void*)&K8u, (void*)&accs,
                         (void*)&tgt, (void*)&pred, (void*)&out4 };
        hipError_t err = hipLaunchCooperativeKernel(
                reinterpret_cast<void*>(k_sink), dim3(1024), blk, args, 0, stream);
        if (err == hipSuccess) return;

        // fallback 1: proven multi-launch fp8 path
        unsigned char* K8 = (unsigned char*)ws;
        float* u = (float*)(ws + k8b + accb);
        float* v = u + 65536;
        k_zero<<<dim3(768), blk, 0, stream>>>(accs, 3 * 65536);
        k_exp8c<<<dim3(1024), blk, 0, stream>>>((const float4*)C, regp,
                (unsigned*)K8, accs);
        for (int it = 0; it < 50; ++it) {
            float* ain = accs + (size_t)(it % 3) * 65536;
            float* aout = accs + (size_t)((it + 1) % 3) * 65536;
            float* az = accs + (size_t)((it + 2) % 3) * 65536;
            k_fused<<<dim3(1024), blk, 0, stream>>>(K8, ain, aout, az,
                    tgt, pred, u);
        }
        k_vfin<<<dim3(256), blk, 0, stream>>>(accs + 2 * 65536, tgt, v, 65536);
        k_poutUC<<<dim3(65536), blk, 0, stream>>>(C, regp, u, v, out);
    } else {
        float* u = (float*)ws;
        float* v = u + 65536;
        k_ones<<<dim3(256), blk, 0, stream>>>(u, 65536);
        for (int it = 0; it < 50; ++it) {
            k_ktuC<<<dim3(8, 64), blk, 0, stream>>>(C, regp, u, tgt, v);
            k_kvC<<<dim3(16384), blk, 0, stream>>>(C, regp, v, pred, u);
        }
        k_ktuC<<<dim3(8, 64), blk, 0, stream>>>(C, regp, u, tgt, v);
        k_poutUC<<<dim3(65536), blk, 0, stream>>>(C, regp, u, v, out);
    }
}

// Round 5
// 5574.401 us; speedup vs baseline: 1.9741x; 1.9741x over previous
//
#include <hip/hip_runtime.h>
#include <cstdint>
#include <cstddef>

// Sinkhorn: B=64, P=1024, T=1024, 50 iterations.
// R7: back to the PROVEN multi-launch fused structure (R3, 1367us) after
// the persistent-kernel experiment showed grid.sync costs ~200us/sync at
// 1024 blocks (R6: 11ms, VALUBusy 4.5%). Two changes inside the proven
// iteration kernel:
//   1. 8-deep rolling prefetch of the 16 K-rows per wave (was ~2 in
//      flight, VGPR=56): hides LLC/L2 latency; __launch_bounds__(256,4).
//   2. Hardware fp8 decode via v_cvt_pk_f32_fp8 (gfx950 OCP e4m3 matches
//      our encoder), guarded by __has_builtin with raw-bits fallback.
// Everything else (encode+acc0 fold, 3-buffer acc rotation with in-kernel
// zeroing, LDS reduce + atomics, f32 final pass) is byte-identical to R3.

#define DEVI static __device__ __forceinline__

// fp8 e4m3 encode (sign=0). Input pre-scaled by 256: f in (0, 256].
DEVI unsigned char f2fp8(float f) {
    if (f >= 0.015625f) {                      // normal fp8
        unsigned u = __float_as_uint(f);
        u += 0x7FFFFu + ((u >> 20) & 1u);      // RNE into 3-bit mantissa
        int e = (int)(u >> 23) - 127;
        return (unsigned char)(((e + 7) << 3) | ((u >> 20) & 7u));
    } else {                                   // subnormal: round(f*512)
        int n = (int)(f * 512.0f + 0.5f);      // n==8 aliases to e=1,m=0: correct
        return (unsigned char)n;
    }
}
// raw decode fallback: returns K * 2^-112
DEVI float fp8raw(unsigned b) { return __uint_as_float((b & 0x7Fu) << 20); }

typedef __attribute__((ext_vector_type(2))) float f32x2;

#ifndef __has_builtin
#define __has_builtin(x) 0
#endif
#if __has_builtin(__builtin_amdgcn_cvt_pk_f32_fp8)
// HW decode of OCP e4m3 -> true value (encoder stored 256*K) => descale 2^-8
#define K_DESCALE 0x1.0p-8f
#define DEC_LO(w) __builtin_amdgcn_cvt_pk_f32_fp8((int)(w), false)
#define DEC_HI(w) __builtin_amdgcn_cvt_pk_f32_fp8((int)(w), true)
#else
// raw-bits decode -> K * 2^-112 => descale 2^112
#define K_DESCALE 0x1.0p112f
DEVI f32x2 dec_lo_(unsigned w) { f32x2 r; r.x = fp8raw(w); r.y = fp8raw(w >> 8); return r; }
DEVI f32x2 dec_hi_(unsigned w) { f32x2 r; r.x = fp8raw(w >> 16); r.y = fp8raw(w >> 24); return r; }
#define DEC_LO(w) dec_lo_(w)
#define DEC_HI(w) dec_hi_(w)
#endif

DEVI void atomicAddF(float* p, float v) {
#ifdef __HIP_PLATFORM_AMD__
    unsafeAtomicAdd(p, v);   // native global_atomic_add_f32
#else
    atomicAdd(p, v);
#endif
}

__global__ __launch_bounds__(256) void k_zero(float* __restrict__ p, int n) {
    int i = blockIdx.x * 256 + threadIdx.x;
    if (i < n) p[i] = 0.0f;
}
__global__ __launch_bounds__(256) void k_ones(float* __restrict__ p, int n) {
    int i = blockIdx.x * 256 + threadIdx.x;
    if (i < n) p[i] = 1.0f;
}

// exp + fp8 encode + fold in acc0 = K^T 1 (u0 = ones) via atomics.
// grid 1024: batch b = bx>>4, rows (bx&15)+16k; thread tid owns cols
// 4tid..4tid+3 for every row it visits (col partials in registers).
__global__ __launch_bounds__(256) void k_exp8c(const float4* __restrict__ C4,
        const float* __restrict__ regp, unsigned* __restrict__ K8,
        float* __restrict__ acc0) {
    const float negi = -1.0f / regp[0];
    const int tid = threadIdx.x;
    const int b = blockIdx.x >> 4;
    const int r0 = blockIdx.x & 15;
    float a0 = 0.f, a1 = 0.f, a2 = 0.f, a3 = 0.f;
    const size_t bbase = (((size_t)b) << 18) + tid;   // float4 units
    #pragma unroll 4
    for (int k = 0; k < 64; ++k) {
        const size_t idx = bbase + ((size_t)((k << 4) + r0) << 8);
        float4 c = C4[idx];
        unsigned p = (unsigned)f2fp8(__expf(c.x * negi) * 256.f)
                   | ((unsigned)f2fp8(__expf(c.y * negi) * 256.f) << 8)
                   | ((unsigned)f2fp8(__expf(c.z * negi) * 256.f) << 16)
                   | ((unsigned)f2fp8(__expf(c.w * negi) * 256.f) << 24);
        K8[idx] = p;
        f32x2 q;
        q = DEC_LO(p); a0 += q.x; a1 += q.y;    // scale-consistent with
        q = DEC_HI(p); a2 += q.x; a3 += q.y;    // the iteration decode
    }
    float* a = acc0 + (b << 10) + (tid << 2);
    atomicAddF(a + 0, a0); atomicAddF(a + 1, a1);
    atomicAddF(a + 2, a2); atomicAddF(a + 3, a3);
}

// Fused Sinkhorn step (one launch per iteration). grid 1024 x 256:
// batch b = bx>>4, 64 rows/block, 4 waves x 16 rows. Reads acc_in
// (K^T u, scaled), computes v + u_new, accumulates K^T u_new -> acc_out,
// zeros acc_z slice (3-buffer rotation).
__global__ __launch_bounds__(256, 4) void k_fused2(const unsigned char* __restrict__ K8,
        const float* __restrict__ acc_in, float* __restrict__ acc_out,
        float* __restrict__ acc_z,
        const float* __restrict__ tgt, const float* __restrict__ pred,
        float* __restrict__ u) {
    __shared__ float sv[1024];
    __shared__ float red[4 * 1088];   // per-wave partials, stride 17: 2-way banks
    const int tid = threadIdx.x;
    const int b = blockIdx.x >> 4;
    const int rb = blockIdx.x & 15;
    {   // v[t] = tgt/(acc_in*DESCALE); acc row is 4KB, L2-hot (16 readers)
        const float* ai = acc_in + (b << 10);
        const float* tg = tgt + (b << 10);
        #pragma unroll
        for (int q = 0; q < 4; ++q) {
            const int t = tid + (q << 8);
            sv[t] = tg[t] / (ai[t] * K_DESCALE);
        }
        if (tid < 64) acc_z[(blockIdx.x << 6) + tid] = 0.f;
    }
    __syncthreads();
    const int w = tid >> 6, l = tid & 63;
    const int row0 = (b << 10) + (rb << 6) + (w << 4);
    const float4 v0 = *(const float4*)(sv + (l << 4));
    const float4 v1 = *(const float4*)(sv + (l << 4) + 4);
    const float4 v2 = *(const float4*)(sv + (l << 4) + 8);
    const float4 v3 = *(const float4*)(sv + (l << 4) + 12);

    // 8-deep rolling prefetch of the wave's 16 K-rows (static after unroll)
    const unsigned char* kbase = K8 + ((size_t)row0 << 10) + (l << 4);
    uint4 kk[16];
    #pragma unroll
    for (int r = 0; r < 8; ++r)
        kk[r] = *(const uint4*)(kbase + ((size_t)r << 10));

    float r00=0,r01=0,r02=0,r03=0,r04=0,r05=0,r06=0,r07=0;
    float r08=0,r09=0,r10=0,r11=0,r12=0,r13=0,r14=0,r15=0;
    #pragma unroll
    for (int r = 0; r < 16; ++r) {
        if (r < 8) kk[r + 8] = *(const uint4*)(kbase + ((size_t)(r + 8) << 10));
        const uint4 k = kk[r];
        f32x2 p;
        p = DEC_LO(k.x); const float f0 = p.x, f1 = p.y;
        p = DEC_HI(k.x); const float f2 = p.x, f3 = p.y;
        p = DEC_LO(k.y); const float f4 = p.x, f5 = p.y;
        p = DEC_HI(k.y); const float f6 = p.x, f7 = p.y;
        p = DEC_LO(k.z); const float f8 = p.x, f9 = p.y;
        p = DEC_HI(k.z); const float fa = p.x, fb = p.y;
        p = DEC_LO(k.w); const float fc = p.x, fd = p.y;
        p = DEC_HI(k.w); const float fe = p.x, ff = p.y;
        // 4 independent FMA chains for ILP, then 2-level combine
        float sA = f0 * v0.x, sB = f1 * v0.y, sC = f2 * v0.z, sD = f3 * v0.w;
        sA += f4 * v1.x; sB += f5 * v1.y; sC += f6 * v1.z; sD += f7 * v1.w;
        sA += f8 * v2.x; sB += f9 * v2.y; sC += fa * v2.z; sD += fb * v2.w;
        sA += fc * v3.x; sB += fd * v3.y; sC += fe * v3.z; sD += ff * v3.w;
        float s = (sA + sB) + (sC + sD);
        #pragma unroll
        for (int m = 32; m >= 1; m >>= 1) s += __shfl_xor(s, m, 64);
        const float un = pred[row0 + r] / (s * K_DESCALE);
        if (l == 0) u[row0 + r] = un;
        r00 += f0*un; r01 += f1*un; r02 += f2*un; r03 += f3*un;
        r04 += f4*un; r05 += f5*un; r06 += f6*un; r07 += f7*un;
        r08 += f8*un; r09 += f9*un; r10 += fa*un; r11 += fb*un;
        r12 += fc*un; r13 += fd*un; r14 += fe*un; r15 += ff*un;
    }
    {   // lane l owns t = 16l+j; stride-17: bank = (17l+j)%32, 2-way only
        const int base = w * 1088 + l * 17;
        red[base + 0] = r00;  red[base + 1] = r01;  red[base + 2] = r02;  red[base + 3] = r03;
        red[base + 4] = r04;  red[base + 5] = r05;  red[base + 6] = r06;  red[base + 7] = r07;
        red[base + 8] = r08;  red[base + 9] = r09;  red[base + 10] = r10; red[base + 11] = r11;
        red[base + 12] = r12; red[base + 13] = r13; red[base + 14] = r14; red[base + 15] = r15;
    }
    __syncthreads();
    float* ao = acc_out + (b << 10);
    #pragma unroll
    for (int q = 0; q < 4; ++q) {
        const int t = tid + (q << 8);
        const int idx = (t >> 4) * 17 + (t & 15);
        float s2 = red[idx] + red[idx + 1088] + red[idx + 2176] + red[idx + 3264];
        atomicAddF(ao + t, s2);   // 16 adds per address total
    }
}

__global__ __launch_bounds__(256) void k_vfin(const float* __restrict__ acc,
        const float* __restrict__ tgt, float* __restrict__ v, int n) {
    int i = blockIdx.x * 256 + threadIdx.x;
    if (i < n) v[i] = tgt[i] / (acc[i] * K_DESCALE);
}

// P = u * exp(-C/reg) * v  (f32 K)
__global__ __launch_bounds__(256) void k_poutUC(const float* __restrict__ C,
        const float* __restrict__ regp, const float* __restrict__ u,
        const float* __restrict__ v, float* __restrict__ out) {
    const size_t row = blockIdx.x;
    const int b = (int)(row >> 10);
    const int t = threadIdx.x << 2;
    const float up = u[row];
    const float negi = -1.0f / regp[0];
    const float4 vv = *(const float4*)(v + (b << 10) + t);
    const float4 c4 = *(const float4*)(C + (row << 10) + t);
    float4 o = make_float4(up * __expf(c4.x * negi) * vv.x,
                           up * __expf(c4.y * negi) * vv.y,
                           up * __expf(c4.z * negi) * vv.z,
                           up * __expf(c4.w * negi) * vv.w);
    *(float4*)(out + (row << 10) + t) = o;
}

// ======== fallback: tiny workspace, recompute exp from C each pass ========
__global__ __launch_bounds__(256) void k_ktuC(const float* __restrict__ C,
        const float* __restrict__ regp, const float* __restrict__ u,
        const float* __restrict__ tgt, float* __restrict__ v) {
    __shared__ float su[1024];
    __shared__ float4 red[256];
    const int b = blockIdx.y;
    const int t0 = blockIdx.x * 128;
    const int tid = threadIdx.x;
    ((float4*)su)[tid] = ((const float4*)(u + (b << 10)))[tid];
    __syncthreads();
    const int tt = tid & 31;
    const int pg = tid >> 5;
    const int t = t0 + tt * 4;
    float4 acc = make_float4(0.f, 0.f, 0.f, 0.f);
    const float negi = -1.0f / regp[0];
    const float* Cp = C + (((size_t)b) << 20) + ((size_t)pg << 10) + t;
    #pragma unroll 4
    for (int p = pg; p < 1024; p += 8) {
        float4 c4 = *(const float4*)Cp;
        float up = su[p];
        acc.x += __expf(c4.x * negi) * up;
        acc.y += __expf(c4.y * negi) * up;
        acc.z += __expf(c4.z * negi) * up;
        acc.w += __expf(c4.w * negi) * up;
        Cp += (size_t)8 << 10;
    }
    red[tid] = acc;
    __syncthreads();
    if (tid < 32) {
        float4 s = red[tid];
        #pragma unroll
        for (int g = 1; g < 8; ++g) {
            float4 r = red[tid + (g << 5)];
            s.x += r.x; s.y += r.y; s.z += r.z; s.w += r.w;
        }
        const int tw = t0 + tid * 4;
        const float4 tg = *(const float4*)(tgt + (b << 10) + tw);
        *(float4*)(v + (b << 10) + tw) =
            make_float4(tg.x / s.x, tg.y / s.y, tg.z / s.z, tg.w / s.w);
    }
}

__global__ __launch_bounds__(256) void k_kvC(const float* __restrict__ C,
        const float* __restrict__ regp, const float* __restrict__ v,
        const float* __restrict__ pred, float* __restrict__ u) {
    __shared__ float sv[1024];
    const int tid = threadIdx.x;
    const int row0 = blockIdx.x << 2;
    const int b = row0 >> 10;
    ((float4*)sv)[tid] = ((const float4*)(v + (b << 10)))[tid];
    __syncthreads();
    const int w = tid >> 6, l = tid & 63;
    const size_t row = (size_t)row0 + w;
    float s = 0.f;
    const float negi = -1.0f / regp[0];
    const float* Cr = C + (row << 10);
    #pragma unroll
    for (int i = 0; i < 4; ++i) {
        const int t = (i << 8) + (l << 2);
        float4 c4 = *(const float4*)(Cr + t);
        float4 vv = *(const float4*)(sv + t);
        s += __expf(c4.x * negi) * vv.x + __expf(c4.y * negi) * vv.y
           + __expf(c4.z * negi) * vv.z + __expf(c4.w * negi) * vv.w;
    }
    #pragma unroll
    for (int m = 32; m >= 1; m >>= 1) s += __shfl_xor(s, m, 64);
    if (l == 0) u[row] = pred[row] / s;
}

extern "C" void kernel_launch(void* const* d_in, const int* in_sizes, int n_in,
                              void* d_out, int out_size, void* d_ws, size_t ws_size,
                              hipStream_t stream) {
    const float* pred = (const float*)d_in[0];
    const float* tgt  = (const float*)d_in[1];
    const float* C    = (const float*)d_in[2];
    const float* regp = (const float*)d_in[3];
    float* out = (float*)d_out;

    const size_t k8b  = (size_t)64 * 1024 * 1024;         // 64 MB fp8 K
    const size_t accb = (size_t)3 * 65536 * 4;            // 768 KB acc[3]
    char* ws = (char*)d_ws;
    const dim3 blk(256);

    if (ws_size >= k8b + accb + (size_t)2 * 65536 * 4) {
        unsigned char* K8 = (unsigned char*)ws;
        float* accs = (float*)(ws + k8b);
        float* u = (float*)(ws + k8b + accb);
        float* v = u + 65536;

        k_zero<<<dim3(768), blk, 0, stream>>>(accs, 3 * 65536);
        k_exp8c<<<dim3(1024), blk, 0, stream>>>((const float4*)C, regp,
                (unsigned*)K8, accs);                     // acc0 = K^T 1
        for (int it = 0; it < 50; ++it) {
            float* ain = accs + (size_t)(it % 3) * 65536;
            float* aout = accs + (size_t)((it + 1) % 3) * 65536;
            float* az = accs + (size_t)((it + 2) % 3) * 65536;
            k_fused2<<<dim3(1024), blk, 0, stream>>>(K8, ain, aout, az,
                    tgt, pred, u);
        }
        // after it=49: acc[(49+1)%3] = acc[2] holds K^T u_final
        k_vfin<<<dim3(256), blk, 0, stream>>>(accs + 2 * 65536, tgt, v, 65536);
        k_poutUC<<<dim3(65536), blk, 0, stream>>>(C, regp, u, v, out);
    } else {
        float* u = (float*)ws;
        float* v = u + 65536;
        k_ones<<<dim3(256), blk, 0, stream>>>(u, 65536);
        for (int it = 0; it < 50; ++it) {
            k_ktuC<<<dim3(8, 64), blk, 0, stream>>>(C, regp, u, tgt, v);
            k_kvC<<<dim3(16384), blk, 0, stream>>>(C, regp, v, pred, u);
        }
        k_ktuC<<<dim3(8, 64), blk, 0, stream>>>(C, regp, u, tgt, v);
        k_poutUC<<<dim3(65536), blk, 0, stream>>>(C, regp, u, v, out);
    }
}